// Round 1
// baseline (1444.251 us; speedup 1.0000x reference)
//
#include <hip/hip_runtime.h>
#include <cstdint>
#include <cstddef>

#define ND 8000
#define NL 16000
#define NE 60000
#define NM 50000

#define BM 64
#define BN 64
#define BK 16

// ---------------- GEMM: C = A[M,K] @ B[K,N] (+bias[n]) (+emb[nid[m],n]) ----------------
__global__ __launch_bounds__(256) void gemm_kernel(
    const float* __restrict__ A, const float* __restrict__ B,
    const float* __restrict__ bias, const float* __restrict__ emb, const int* __restrict__ nid,
    float* __restrict__ Cm, int M, int N, int K)
{
    __shared__ float As[BK][BM + 4];
    __shared__ float Bs[BK][BN + 4];
    const int tid = threadIdx.x;
    const int tx = tid & 15, ty = tid >> 4;
    const int bm = blockIdx.y * BM, bn = blockIdx.x * BN;
    float acc[4][4] = {};
    for (int k0 = 0; k0 < K; k0 += BK) {
#pragma unroll
        for (int i = 0; i < 4; ++i) {
            int idx = tid + i * 256;
            int ml = idx >> 4, kl = idx & 15;
            int gm = bm + ml, gk = k0 + kl;
            As[kl][ml] = (gm < M && gk < K) ? A[(size_t)gm * K + gk] : 0.f;
        }
#pragma unroll
        for (int i = 0; i < 4; ++i) {
            int idx = tid + i * 256;
            int kl = idx >> 6, nl = idx & 63;
            int gk = k0 + kl, gn = bn + nl;
            Bs[kl][nl] = (gk < K && gn < N) ? B[(size_t)gk * N + gn] : 0.f;
        }
        __syncthreads();
#pragma unroll
        for (int k = 0; k < BK; ++k) {
            float4 av = *(const float4*)&As[k][ty * 4];
            float4 bv = *(const float4*)&Bs[k][tx * 4];
            float a4[4] = {av.x, av.y, av.z, av.w};
            float b4[4] = {bv.x, bv.y, bv.z, bv.w};
#pragma unroll
            for (int i = 0; i < 4; ++i)
#pragma unroll
                for (int j = 0; j < 4; ++j)
                    acc[i][j] += a4[i] * b4[j];
        }
        __syncthreads();
    }
#pragma unroll
    for (int i = 0; i < 4; ++i) {
        int gm = bm + ty * 4 + i;
        if (gm >= M) continue;
        int gn0 = bn + tx * 4;
        float4 v;
        float* vp = &v.x;
#pragma unroll
        for (int j = 0; j < 4; ++j) {
            float x = acc[i][j];
            int gn = gn0 + j;
            if (bias) x += bias[gn];
            if (emb) x += emb[(size_t)nid[gm] * N + gn];
            vp[j] = x;
        }
        if (gn0 + 3 < N) *(float4*)&Cm[(size_t)gm * N + gn0] = v;
    }
}

// ---------------- fold: Wfold[f][k][h] = sum_c W[k, h*C+c] * a[h, c], f in 0..3 ----------------
__global__ void fold_kernel(const float* __restrict__ Ws, const float* __restrict__ Wd,
                            const float* __restrict__ as_, const float* __restrict__ ad_,
                            float* __restrict__ fw, int Ntot, int C)
{
    int gid = blockIdx.x * blockDim.x + threadIdx.x;
    if (gid >= 4 * 128 * 16) return;
    int f = gid / 2048, rem = gid % 2048;
    int k = rem >> 4, h = rem & 15;
    const float* W = (f == 0 || f == 2) ? Ws : Wd;
    const float* a = (f == 0 || f == 2) ? as_ : ad_;
    if (f >= 2) { W += 128 * Ntot; a += 16 * C; }
    float s = 0.f;
    for (int c = 0; c < C; ++c) s += W[(size_t)k * Ntot + h * C + c] * a[h * C + c];
    fw[gid] = s;
}

// ---------------- score: out[n,16] = H[n,128] @ Wf[128,16] ----------------
__global__ __launch_bounds__(256) void score_kernel(
    const float* __restrict__ Hf, const float* __restrict__ Wf, float* __restrict__ out, int n)
{
    __shared__ float hs[16 * 128];
    __shared__ float ws[128 * 16];
    int tid = threadIdx.x;
    int n0 = blockIdx.x * 16;
#pragma unroll
    for (int i = 0; i < 8; ++i) {
        int idx = tid + i * 256;
        int nl = idx >> 7, k = idx & 127;
        int gn = n0 + nl;
        hs[idx] = (gn < n) ? Hf[(size_t)gn * 128 + k] : 0.f;
        ws[idx] = Wf[idx];
    }
    __syncthreads();
    int nl = tid >> 4, h = tid & 15;
    float s = 0.f;
    for (int k = 0; k < 128; ++k) s += hs[nl * 128 + k] * ws[k * 16 + h];
    int gn = n0 + nl;
    if (gn < n) out[gn * 16 + h] = s;
}

// ---------------- CSR build ----------------
__global__ void hist_kernel(const int* __restrict__ esrc, const int* __restrict__ edst,
                            int* __restrict__ degl, int* __restrict__ degd)
{
    int e = blockIdx.x * blockDim.x + threadIdx.x;
    if (e >= NE) return;
    atomicAdd(&degl[edst[e]], 1);
    atomicAdd(&degd[esrc[e]], 1);
}

__global__ __launch_bounds__(1024) void scan_kernel(const int* __restrict__ deg, int* __restrict__ off, int n)
{
    __shared__ int ps[1024];
    int tid = threadIdx.x;
    int chunk = (n + 1023) >> 10;
    int start = tid * chunk, end = min(start + chunk, n);
    int p = 0;
    for (int i = start; i < end; ++i) p += deg[i];
    ps[tid] = p;
    __syncthreads();
    for (int o = 1; o < 1024; o <<= 1) {
        int v = (tid >= o) ? ps[tid - o] : 0;
        __syncthreads();
        ps[tid] += v;
        __syncthreads();
    }
    int run = ps[tid] - p;
    for (int i = start; i < end; ++i) { off[i] = run; run += deg[i]; }
    if (tid == 1023) off[n] = ps[1023];
}

__global__ void scatter_kernel(const int* __restrict__ esrc, const int* __restrict__ edst,
                               const int* __restrict__ offl, const int* __restrict__ offd,
                               int* __restrict__ curl, int* __restrict__ curd,
                               int* __restrict__ csrl, int* __restrict__ csrd)
{
    int e = blockIdx.x * blockDim.x + threadIdx.x;
    if (e >= NE) return;
    int dl = edst[e]; int p = atomicAdd(&curl[dl], 1); csrl[offl[dl] + p] = e;
    int dd = esrc[e]; int q = atomicAdd(&curd[dd], 1); csrd[offd[dd] + q] = e;
}

// ---------------- fused GAT aggregate: softmax + weighted sum + bias + relu + head-mean ----------------
// R = Ntot/256 channels per thread; head of a thread = tid/16 (R divides C, C = Ntot/16)
template <int R>
__global__ __launch_bounds__(256) void aggregate_kernel(
    const float* __restrict__ zs, const float* __restrict__ ss, const float* __restrict__ sd,
    const int* __restrict__ off, const int* __restrict__ csr, const int* __restrict__ srcidx,
    const float* __restrict__ bias, float* __restrict__ out, int Ntot, int C)
{
    __shared__ float m_s[16], s_s[16];
    __shared__ float alpha_s[16][16];
    __shared__ int src_s[16];
    __shared__ float lds_out[2048];
    const int d = blockIdx.x;
    const int tid = threadIdx.x;
    const int e0 = off[d], e1 = off[d + 1];

    if (tid < 16) {
        int h = tid;
        float sdv = sd[d * 16 + h];
        float m = -1e30f;
        for (int e = e0; e < e1; ++e) {
            int sn = srcidx[csr[e]];
            float al = ss[sn * 16 + h] + sdv;
            al = al >= 0.f ? al : 0.2f * al;
            m = fmaxf(m, al);
        }
        float s = 0.f;
        for (int e = e0; e < e1; ++e) {
            int sn = srcidx[csr[e]];
            float al = ss[sn * 16 + h] + sdv;
            al = al >= 0.f ? al : 0.2f * al;
            s += expf(al - m);
        }
        m_s[h] = m;
        s_s[h] = s + 1e-16f;
    }
    __syncthreads();

    float acc[R];
#pragma unroll
    for (int r = 0; r < R; ++r) acc[r] = 0.f;
    const int hsel = tid >> 4;

    for (int ce = e0; ce < e1; ce += 16) {
        int nc = min(16, e1 - ce);
        if (tid < nc * 16) {
            int ei = tid >> 4, h = tid & 15;
            int sn = srcidx[csr[ce + ei]];
            float al = ss[sn * 16 + h] + sd[d * 16 + h];
            al = al >= 0.f ? al : 0.2f * al;
            alpha_s[ei][h] = expf(al - m_s[h]) / s_s[h];
            if (h == 0) src_s[ei] = sn;
        }
        __syncthreads();
        for (int ei = 0; ei < nc; ++ei) {
            float a = alpha_s[ei][hsel];
            const float* zp = zs + (size_t)src_s[ei] * Ntot + tid * R;
            if (R == 8) {
                float4 v0 = *(const float4*)zp;
                float4 v1 = *(const float4*)(zp + 4);
                acc[0] += a * v0.x; acc[1] += a * v0.y; acc[2] += a * v0.z; acc[3] += a * v0.w;
                acc[4] += a * v1.x; acc[5] += a * v1.y; acc[6] += a * v1.z; acc[7] += a * v1.w;
            } else {
                float2 v = *(const float2*)zp;
                acc[0] += a * v.x; acc[1] += a * v.y;
            }
        }
        __syncthreads();
    }

#pragma unroll
    for (int r = 0; r < R; ++r) {
        int ch = tid * R + r;
        lds_out[ch] = fmaxf(acc[r] + bias[ch], 0.f);
    }
    __syncthreads();
    if (tid < C) {
        float s = 0.f;
        for (int h = 0; h < 16; ++h) s += lds_out[h * C + tid];
        out[(size_t)d * C + tid] = s * (1.f / 16.f);
    }
}

// ---------------- penalty: out[n,32] = h[n,32] * exp(h[n,:] @ pw + pb) ----------------
__global__ void penalty_kernel(const float* __restrict__ h, const float* __restrict__ pw,
                               const float* __restrict__ pb, float* __restrict__ out, int n)
{
    int i = blockIdx.x * blockDim.x + threadIdx.x;
    if (i >= n) return;
    float t = pb[0];
    const float* hp = h + (size_t)i * 32;
#pragma unroll
    for (int c = 0; c < 32; ++c) t += hp[c] * pw[c];
    float f = expf(t);
    float* op = out + (size_t)i * 32;
#pragma unroll
    for (int c = 0; c < 32; ++c) op[c] = hp[c] * f;
}

// ---------------- final MLP on label edges ----------------
__global__ __launch_bounds__(256) void mlp_kernel(
    const float* __restrict__ hd, const float* __restrict__ hl,
    const int* __restrict__ ls, const int* __restrict__ ld,
    const float* __restrict__ w1, const float* __restrict__ b1,
    const float* __restrict__ w2, const float* __restrict__ b2,
    float* __restrict__ out, int M)
{
    __shared__ float w1s[64 * 64];
    __shared__ float b1s[64];
    __shared__ float w2s[64];
    int tid = threadIdx.x;
#pragma unroll
    for (int i = 0; i < 16; ++i) w1s[tid + i * 256] = w1[tid + i * 256];
    if (tid < 64) { b1s[tid] = b1[tid]; w2s[tid] = w2[tid]; }
    __syncthreads();
    int m = blockIdx.x * 256 + tid;
    if (m >= M) return;
    float f[64];
    const float* hp = hd + (size_t)ls[m] * 32;
    const float* lp = hl + (size_t)ld[m] * 32;
#pragma unroll
    for (int c = 0; c < 32; ++c) { f[c] = hp[c]; f[32 + c] = lp[c]; }
    float o = b2[0];
    for (int j = 0; j < 64; ++j) {
        float hj = b1s[j];
#pragma unroll
        for (int k = 0; k < 64; ++k) hj += f[k] * w1s[k * 64 + j];
        hj = fmaxf(hj, 0.f);
        o += hj * w2s[j];
    }
    out[m] = o;
}

extern "C" void kernel_launch(void* const* d_in, const int* in_sizes, int n_in,
                              void* d_out, int out_size, void* d_ws, size_t ws_size,
                              hipStream_t stream)
{
    const float* x_d = (const float*)d_in[0];
    const float* x_l = (const float*)d_in[1];
    const int* node_id_d = (const int*)d_in[2];
    const int* node_id_l = (const int*)d_in[3];
    const int* edge_src = (const int*)d_in[4];
    const int* edge_dst = (const int*)d_in[5];
    const int* label_src = (const int*)d_in[6];
    const int* label_dst = (const int*)d_in[7];
    const float* emb_d = (const float*)d_in[8];
    const float* emb_l = (const float*)d_in[9];
    const float* lin_dw = (const float*)d_in[10];
    const float* lin_db = (const float*)d_in[11];
    const float* lin_lw = (const float*)d_in[12];
    const float* lin_lb = (const float*)d_in[13];
    const float* Ws[3] = {(const float*)d_in[14], (const float*)d_in[19], (const float*)d_in[24]};
    const float* Wd[3] = {(const float*)d_in[15], (const float*)d_in[20], (const float*)d_in[25]};
    const float* as_[3] = {(const float*)d_in[16], (const float*)d_in[21], (const float*)d_in[26]};
    const float* ad_[3] = {(const float*)d_in[17], (const float*)d_in[22], (const float*)d_in[27]};
    const float* bb[3] = {(const float*)d_in[18], (const float*)d_in[23], (const float*)d_in[28]};
    const int NtotL[3] = {2048, 2048, 512};
    const float* pw = (const float*)d_in[29];
    const float* pb = (const float*)d_in[30];
    const float* fc1w = (const float*)d_in[31];
    const float* fc1b = (const float*)d_in[32];
    const float* fc2w = (const float*)d_in[33];
    const float* fc2b = (const float*)d_in[34];

    char* wsb = (char*)d_ws;
    size_t woff = 0;
    auto carve = [&](size_t bytes) -> void* {
        woff = (woff + 255) & ~(size_t)255;
        void* p = wsb + woff;
        woff += bytes;
        return p;
    };
    float* hdA = (float*)carve((size_t)ND * 128 * 4);
    float* hdB = (float*)carve((size_t)ND * 128 * 4);
    float* hlA = (float*)carve((size_t)NL * 128 * 4);
    float* hlB = (float*)carve((size_t)NL * 128 * 4);
    float* zs  = (float*)carve((size_t)NL * 2048 * 4);
    float* ssb = (float*)carve((size_t)NL * 16 * 4);
    float* sdb = (float*)carve((size_t)NL * 16 * 4);
    float* fw  = (float*)carve((size_t)4 * 2048 * 4);
    int* degl = (int*)carve((size_t)NL * 4);
    int* degd = (int*)carve((size_t)ND * 4);
    int* curl = (int*)carve((size_t)NL * 4);
    int* curd = (int*)carve((size_t)ND * 4);
    int* offl = (int*)carve((size_t)(NL + 1) * 4);
    int* offd = (int*)carve((size_t)(ND + 1) * 4);
    int* csrl = (int*)carve((size_t)NE * 4);
    int* csrd = (int*)carve((size_t)NE * 4);
    float* hdp = (float*)carve((size_t)ND * 32 * 4);
    float* hlp = (float*)carve((size_t)NL * 32 * 4);

    hipMemsetAsync(degl, 0, NL * 4, stream);
    hipMemsetAsync(degd, 0, ND * 4, stream);
    hipMemsetAsync(curl, 0, NL * 4, stream);
    hipMemsetAsync(curd, 0, ND * 4, stream);

    hist_kernel<<<(NE + 255) / 256, 256, 0, stream>>>(edge_src, edge_dst, degl, degd);
    scan_kernel<<<1, 1024, 0, stream>>>(degl, offl, NL);
    scan_kernel<<<1, 1024, 0, stream>>>(degd, offd, ND);
    scatter_kernel<<<(NE + 255) / 256, 256, 0, stream>>>(edge_src, edge_dst, offl, offd, curl, curd, csrl, csrd);

    // input linears + embedding add
    gemm_kernel<<<dim3(128 / BN, ND / BM), 256, 0, stream>>>(x_d, lin_dw, lin_db, emb_d, node_id_d, hdA, ND, 128, 412);
    gemm_kernel<<<dim3(128 / BN, NL / BM), 256, 0, stream>>>(x_l, lin_lw, lin_lb, emb_l, node_id_l, hlA, NL, 128, 240);

    float* hd_cur = hdA; float* hd_nxt = hdB;
    float* hl_cur = hlA; float* hl_nxt = hlB;
    for (int L = 0; L < 3; ++L) {
        int Ntot = NtotL[L], C = Ntot / 16;
        fold_kernel<<<(4 * 128 * 16 + 255) / 256, 256, 0, stream>>>(Ws[L], Wd[L], as_[L], ad_[L], fw, Ntot, C);

        // edge type 0: disease -> lncrna (dst = lncrna)
        gemm_kernel<<<dim3(Ntot / BN, ND / BM), 256, 0, stream>>>(hd_cur, Ws[L], nullptr, nullptr, nullptr, zs, ND, Ntot, 128);
        score_kernel<<<ND / 16, 256, 0, stream>>>(hd_cur, fw + 0 * 2048, ssb, ND);
        score_kernel<<<NL / 16, 256, 0, stream>>>(hl_cur, fw + 1 * 2048, sdb, NL);
        if (Ntot == 2048)
            aggregate_kernel<8><<<NL, 256, 0, stream>>>(zs, ssb, sdb, offl, csrl, edge_src, bb[L], hl_nxt, Ntot, C);
        else
            aggregate_kernel<2><<<NL, 256, 0, stream>>>(zs, ssb, sdb, offl, csrl, edge_src, bb[L], hl_nxt, Ntot, C);

        // edge type 1: lncrna -> disease (dst = disease)
        gemm_kernel<<<dim3(Ntot / BN, NL / BM), 256, 0, stream>>>(hl_cur, Ws[L] + 128 * Ntot, nullptr, nullptr, nullptr, zs, NL, Ntot, 128);
        score_kernel<<<NL / 16, 256, 0, stream>>>(hl_cur, fw + 2 * 2048, ssb, NL);
        score_kernel<<<ND / 16, 256, 0, stream>>>(hd_cur, fw + 3 * 2048, sdb, ND);
        if (Ntot == 2048)
            aggregate_kernel<8><<<ND, 256, 0, stream>>>(zs, ssb, sdb, offd, csrd, edge_dst, bb[L] + Ntot, hd_nxt, Ntot, C);
        else
            aggregate_kernel<2><<<ND, 256, 0, stream>>>(zs, ssb, sdb, offd, csrd, edge_dst, bb[L] + Ntot, hd_nxt, Ntot, C);

        float* t;
        t = hd_cur; hd_cur = hd_nxt; hd_nxt = t;
        t = hl_cur; hl_cur = hl_nxt; hl_nxt = t;
    }

    penalty_kernel<<<(ND + 255) / 256, 256, 0, stream>>>(hd_cur, pw, pb, hdp, ND);
    penalty_kernel<<<(NL + 255) / 256, 256, 0, stream>>>(hl_cur, pw + 32, pb + 1, hlp, NL);
    mlp_kernel<<<(NM + 255) / 256, 256, 0, stream>>>(hdp, hlp, label_src, label_dst,
                                                     fc1w, fc1b, fc2w, fc2b, (float*)d_out, NM);
}